// Round 6
// baseline (353.446 us; speedup 1.0000x reference)
//
#include <hip/hip_runtime.h>

// Problem constants
#define B_ 2
#define L_ 2048
#define D_ 2048
#define NH_ 16
#define KH_ 8
#define HD_ 128

typedef __attribute__((ext_vector_type(8))) short short8;
typedef __attribute__((ext_vector_type(4))) short short4v;
typedef __attribute__((ext_vector_type(4))) float floatx4;

__device__ __forceinline__ unsigned short f2bf(float f) {
  unsigned u = __float_as_uint(f);
  unsigned r = (u + 0x7fffu + ((u >> 16) & 1u)) >> 16;
  return (unsigned short)r;
}
__device__ __forceinline__ float bf2f(unsigned short h) {
  return __uint_as_float(((unsigned)h) << 16);
}
__device__ __forceinline__ void gl_lds16(const void* g, void* l) {
  __builtin_amdgcn_global_load_lds(
      (const __attribute__((address_space(1))) unsigned int*)g,
      (__attribute__((address_space(3))) unsigned int*)l, 16, 0, 0);
}
// Raw workgroup barrier that does NOT drain vmcnt: only our own LDS ops must be
// complete. __syncthreads() would emit s_waitcnt vmcnt(0) and kill in-flight
// register prefetch (the m97 barrier-drain stall).
__device__ __forceinline__ void barrier_lds_only() {
  asm volatile("s_waitcnt lgkmcnt(0)" ::: "memory");
  __builtin_amdgcn_s_barrier();
}

// ------- fused prep1: cvt x (fp32->bf16) + transpose+convert all weights -------
__global__ __launch_bounds__(256) void prep1(const float* __restrict__ x,
                                             const float* __restrict__ wq,
                                             const float* __restrict__ wk,
                                             const float* __restrict__ wv,
                                             const float* __restrict__ wo,
                                             unsigned short* __restrict__ xb,
                                             unsigned short* __restrict__ wqkv_t,
                                             unsigned short* __restrict__ wo_t) {
  int id = blockIdx.x;
  int t = threadIdx.x;
  if (id < 8192) {
    long i = ((long)id * 256 + t) * 4;
    float4 v = *(const float4*)(x + i);
    ushort4 o;
    o.x = f2bf(v.x); o.y = f2bf(v.y); o.z = f2bf(v.z); o.w = f2bf(v.w);
    *(ushort4*)(xb + i) = o;
    return;
  }
  id -= 8192;
  __shared__ float tile[32][33];
  const float* in;
  unsigned short* out;
  int C, sh;
  if (id < 4096) {
    in = wq; out = wqkv_t; C = 2048; sh = 6;
  } else if (id < 6144) {
    in = wk; out = wqkv_t + 2048L * 2048; C = 1024; sh = 5; id -= 4096;
  } else if (id < 8192) {
    in = wv; out = wqkv_t + 3072L * 2048; C = 1024; sh = 5; id -= 6144;
  } else {
    in = wo; out = wo_t; C = 2048; sh = 6; id -= 8192;
  }
  int c0 = (id & ((1 << sh) - 1)) * 32, r0 = (id >> sh) * 32;
  int tx = t & 31, ty = t >> 5;  // (32, 8)
#pragma unroll
  for (int i = 0; i < 4; i++)
    tile[ty + i * 8][tx] = in[(long)(r0 + ty + i * 8) * C + c0 + tx];
  __syncthreads();
#pragma unroll
  for (int i = 0; i < 4; i++) {
    int oc = ty + i * 8;
    out[(long)(c0 + oc) * 2048 + r0 + tx] = f2bf(tile[tx][oc]);
  }
}

// ------- fused prep2: rmsrope (q,k) + transpose_v -------
__global__ __launch_bounds__(256) void prep2(const unsigned short* __restrict__ qkv,
                                             const int* __restrict__ pos,
                                             const float* __restrict__ qw,
                                             const float* __restrict__ kw,
                                             unsigned short* __restrict__ qo,
                                             unsigned short* __restrict__ ko,
                                             unsigned short* __restrict__ vT) {
  int id = blockIdx.x;
  int t = threadIdx.x;
  if (id < 24576) {
    const int lane = t & 63, w = t >> 6;
    const int gid = id * 4 + w;  // 0 .. 4096*24-1
    const int row = gid / 24;
    const int hd = gid - row * 24;  // 0..15 q, 16..23 k
    const int b = row >> 11, l = row & 2047;
    const unsigned short* src = qkv + (long)row * 4096 + hd * 128;
    float x0 = bf2f(src[lane]);
    float x1 = bf2f(src[lane + 64]);
    float ss = x0 * x0 + x1 * x1;
#pragma unroll
    for (int off = 32; off; off >>= 1) ss += __shfl_xor(ss, off);
    float inv = 1.0f / sqrtf(ss * (1.0f / 128.0f) + 1e-6f);
    const float* nw = (hd < 16) ? qw : kw;
    x0 = nw[lane] * x0 * inv;
    x1 = nw[lane + 64] * x1 * inv;
    float p = (float)pos[row];
    float ang = p * exp2f((float)lane * -0.31143075889f);  // 1/1e6^(lane/64)
    float s, c;
    sincosf(ang, &s, &c);
    float o0 = x0 * c - x1 * s;
    float o1 = x1 * c + x0 * s;
    unsigned short* dst;
    if (hd < 16) {
      const float QSC = 0.08838834764831845f * 1.4426950408889634f;  // H^-0.5 * log2e
      o0 *= QSC;
      o1 *= QSC;
      dst = qo + (((long)b * NH_ + hd) * L_ + l) * HD_;
    } else {
      dst = ko + (((long)b * KH_ + (hd - 16)) * L_ + l) * HD_;
    }
    dst[lane] = f2bf(o0);
    dst[lane + 64] = f2bf(o1);
    return;
  }
  id -= 24576;
  __shared__ unsigned short tile[32][33];
  int l0 = (id & 63) * 32, h0 = ((id >> 6) & 3) * 32;
  int bk = id >> 8;  // b*8 + kh
  int b = bk >> 3, kh = bk & 7;
  int tx = t & 31, ty = t >> 5;
  const unsigned short* src = qkv + (long)b * L_ * 4096 + 3072 + kh * 128;
#pragma unroll
  for (int i = 0; i < 4; i++)
    tile[ty + i * 8][tx] = src[(long)(l0 + ty + i * 8) * 4096 + h0 + tx];
  __syncthreads();
  unsigned short* dst = vT + (long)bk * HD_ * L_;
#pragma unroll
  for (int i = 0; i < 4; i++)
    dst[(long)(h0 + ty + i * 8) * L_ + l0 + tx] = tile[tx][ty + i * 8];
}

// ---------------- 128x128-tile bf16 MFMA GEMM:  C = A(MxK) * Bt(NxK)^T ----------------
// Kept for the output projection: at 256^2 tiling that GEMM would be only 128
// blocks (half the CUs idle). MODE: 0 = fp32 store, 1 = bf16 store.
template <int MODE>
__global__ __launch_bounds__(256, 3) void gemm128(const unsigned short* __restrict__ A,
                                                  const unsigned short* __restrict__ Bt,
                                                  void* __restrict__ C,
                                                  int M, int N, int K) {
  __shared__ unsigned short As[128 * 64];
  __shared__ unsigned short Bs[128 * 64];
  const int t = threadIdx.x;
  const int lane = t & 63, w = t >> 6;
  const int wy = w >> 1, wx = w & 1;
  const int col = lane & 15, quad = lane >> 4;
  const long m0 = (long)blockIdx.y * 128, n0 = (long)blockIdx.x * 128;
  floatx4 acc[4][4];
#pragma unroll
  for (int i = 0; i < 4; i++)
#pragma unroll
    for (int j = 0; j < 4; j++) acc[i][j] = (floatx4)0.0f;
  const int rs = t >> 3, bs = t & 7;  // staging row / 16B-block
  for (int kt = 0; kt < K; kt += 64) {
#pragma unroll
    for (int i = 0; i < 4; i++) {
      int r = i * 32 + rs;
      gl_lds16(A + (m0 + r) * (long)K + kt + ((bs ^ (r & 7)) << 3),
               &As[(i * 32 + w * 8) * 64]);
      gl_lds16(Bt + (n0 + r) * (long)K + kt + ((bs ^ (r & 7)) << 3),
               &Bs[(i * 32 + w * 8) * 64]);
    }
    __syncthreads();
#pragma unroll
    for (int ks = 0; ks < 2; ks++) {
      short8 af[4], bf[4];
#pragma unroll
      for (int mi = 0; mi < 4; mi++) {
        int row = wy * 64 + mi * 16 + col;
        int blk = ks * 4 + quad;
        af[mi] = *(const short8*)&As[row * 64 + ((blk ^ (row & 7)) << 3)];
      }
#pragma unroll
      for (int ni = 0; ni < 4; ni++) {
        int row = wx * 64 + ni * 16 + col;
        int blk = ks * 4 + quad;
        bf[ni] = *(const short8*)&Bs[row * 64 + ((blk ^ (row & 7)) << 3)];
      }
#pragma unroll
      for (int mi = 0; mi < 4; mi++)
#pragma unroll
        for (int ni = 0; ni < 4; ni++)
          acc[mi][ni] = __builtin_amdgcn_mfma_f32_16x16x32_bf16(af[mi], bf[ni],
                                                                acc[mi][ni], 0, 0, 0);
    }
    __syncthreads();
  }
#pragma unroll
  for (int mi = 0; mi < 4; mi++)
#pragma unroll
    for (int r = 0; r < 4; r++) {
      long row = m0 + wy * 64 + mi * 16 + quad * 4 + r;
#pragma unroll
      for (int ni = 0; ni < 4; ni++) {
        long cg = n0 + wx * 64 + ni * 16 + col;
        float val = acc[mi][ni][r];
        if (MODE == 1)
          ((unsigned short*)C)[row * N + cg] = f2bf(val);
        else
          ((float*)C)[row * N + cg] = val;
      }
    }
}

// ---------------- 256x256-tile 8-phase bf16 MFMA GEMM ----------------
// R5 retiming (resubmitted R6 -- R5 bench was an infra failure, never ran):
// stage tile T+2 into the CURRENT buffer c right after each chunk retires.
// Consumption per group T: P0 reads A(T)e={0,2} (a_lo) + B(T) all chunks (b_lo
// rows 0..31 of each); P1 reads B(T) rows 32..63; P2 reads A(T)o={1,3}.
// Retirement: As[c]{0,2} after P0-end barrier; Bs[c] after P1-end; As[c]{1,3}
// after P2-end. Stage slots (all into buffer c, tile T+2):
//   P1 -> A(T+2){0,2}  (7 phases flight to first read at (T+2).P0)
//   P2 -> B(T+2){0,1}  (6 phases)
//   P3 -> B(T+2){2,3}, A(T+2){1,3}  (5 / 7 phases)
// Issue order/group: [Ae][Ba][Bb,Ao] = 8. Queue-derived waits (verified by
// induction: group-entry outstanding = 10 = {Ao(T), 8 of tile T+1}):
//   group-end (needs Ae/Ba/Bb of T+1, issued at T-1): vmcnt(10) drains exactly
//     them; tail T=nt-2 (no stages): vmcnt(2).
//   P2-start (needs Ao(T), staged T-2.P3): vmcnt(10); T=nt-2: 8; T=nt-1: 0.
// Prologue stages tiles 0,1 in steady-state order -> same counts hold at T=0,1.
// vmcnt(10) targets loads with >=5 phases (~1300+ cyc) of flight -- covers the
// ~900-cyc HBM miss that stalled R3's group-end (A staged only 2-3 phases ahead).
template <int MODE>
__global__ __launch_bounds__(512, 2) void gemm256(const unsigned short* __restrict__ A,
                                                  const unsigned short* __restrict__ Bt,
                                                  void* __restrict__ C,
                                                  int M, int N, int K) {
  __shared__ unsigned short As[2][256 * 64];
  __shared__ unsigned short Bs[2][256 * 64];
  const int t = threadIdx.x;
  const int lane = t & 63, w = t >> 6;
  const int wy = w >> 2, wx = w & 3;
  const int col = lane & 15, quad = lane >> 4;
  const long m0 = (long)blockIdx.y * 256, n0 = (long)blockIdx.x * 256;
  const int rs = t >> 3, bs = t & 7;  // staging row-in-chunk / 16B-block
  const int nt = K >> 6;              // K tiles of 64 (needs nt >= 2)

#define SA256(bufi, Tt, h)                                                      \
  gl_lds16(A + (m0 + (h) * 64 + rs) * (long)K + (long)(Tt) * 64 +               \
               ((bs ^ (rs & 7)) << 3),                                          \
           &As[bufi][((h) * 64 + w * 8) * 64])
#define SB256(bufi, Tt, h)                                                      \
  gl_lds16(Bt + (n0 + (h) * 64 + rs) * (long)K + (long)(Tt) * 64 +              \
                ((bs ^ (rs & 7)) << 3),                                         \
           &Bs[bufi][((h) * 64 + w * 8) * 64])

  floatx4 acc[8][4];
#pragma unroll
  for (int i = 0; i < 8; i++)
#pragma unroll
    for (int j = 0; j < 4; j++) acc[i][j] = (floatx4)0.0f;

  // prologue: tiles 0,1 in steady-state order {Ae, Ba, Bb, Ao} x2 (16 loads).
  // vmcnt(10) drains Ae(0),Ba(0),Bb(0) -- exactly what T=0.P0 reads; Ao(0)
  // stays in flight until T=0.P2's vmcnt(10).
  SA256(0, 0, 0); SA256(0, 0, 2);
  SB256(0, 0, 0); SB256(0, 0, 1);
  SB256(0, 0, 2); SB256(0, 0, 3);
  SA256(0, 0, 1); SA256(0, 0, 3);
  if (nt > 1) {
    SA256(1, 1, 0); SA256(1, 1, 2);
    SB256(1, 1, 0); SB256(1, 1, 1);
    SB256(1, 1, 2); SB256(1, 1, 3);
    SA256(1, 1, 1); SA256(1, 1, 3);
    asm volatile("s_waitcnt vmcnt(10)" ::: "memory");
  } else {
    asm volatile("s_waitcnt vmcnt(0)" ::: "memory");
  }
  __builtin_amdgcn_s_barrier();

  for (int T = 0; T < nt; ++T) {
    const int c = T & 1;
    const unsigned short* Ac = As[c];
    const unsigned short* Bc = Bs[c];
    short8 a[4][2], b[4][2];
    const bool stg = (T + 2 < nt);

    // ---- phase 0: read a_lo + b_lo (12 ds_read), no stage, MFMA mi0-3 x ni0-1
#pragma unroll
    for (int mi = 0; mi < 4; mi++)
#pragma unroll
      for (int ks = 0; ks < 2; ks++) {
        int row = wy * 128 + mi * 16 + col;
        a[mi][ks] = *(const short8*)&Ac[row * 64 + (((ks * 4 + quad) ^ (row & 7)) << 3)];
      }
#pragma unroll
    for (int ni = 0; ni < 2; ni++)
#pragma unroll
      for (int ks = 0; ks < 2; ks++) {
        int row = wx * 64 + ni * 16 + col;
        b[ni][ks] = *(const short8*)&Bc[row * 64 + (((ks * 4 + quad) ^ (row & 7)) << 3)];
      }
    __builtin_amdgcn_s_barrier();
    asm volatile("s_waitcnt lgkmcnt(0)" ::: "memory");
    __builtin_amdgcn_s_setprio(1);
#pragma unroll
    for (int mi = 0; mi < 4; mi++)
#pragma unroll
      for (int ni = 0; ni < 2; ni++)
#pragma unroll
        for (int ks = 0; ks < 2; ks++)
          acc[mi][ni] = __builtin_amdgcn_mfma_f32_16x16x32_bf16(a[mi][ks], b[ni][ks],
                                                                acc[mi][ni], 0, 0, 0);
    __builtin_amdgcn_s_setprio(0);
    __builtin_amdgcn_s_barrier();

    // ---- phase 1: read b_hi (4 ds_read), stage A(T+2){0,2} into As[c]
    //      (chunks 0,2 retired at P0-end barrier), MFMA mi0-3 x ni2-3
#pragma unroll
    for (int ni = 2; ni < 4; ni++)
#pragma unroll
      for (int ks = 0; ks < 2; ks++) {
        int row = wx * 64 + ni * 16 + col;
        b[ni][ks] = *(const short8*)&Bc[row * 64 + (((ks * 4 + quad) ^ (row & 7)) << 3)];
      }
    if (stg) { SA256(c, T + 2, 0); SA256(c, T + 2, 2); }
    __builtin_amdgcn_s_barrier();
    asm volatile("s_waitcnt lgkmcnt(0)" ::: "memory");
    __builtin_amdgcn_s_setprio(1);
#pragma unroll
    for (int mi = 0; mi < 4; mi++)
#pragma unroll
      for (int ni = 2; ni < 4; ni++)
#pragma unroll
        for (int ks = 0; ks < 2; ks++)
          acc[mi][ni] = __builtin_amdgcn_mfma_f32_16x16x32_bf16(a[mi][ks], b[ni][ks],
                                                                acc[mi][ni], 0, 0, 0);
    __builtin_amdgcn_s_setprio(0);
    __builtin_amdgcn_s_barrier();

    // ---- phase 2: wait Ao(T) (issued T-2.P3, 7 phases old -> usually free),
    //      read a_hi (8 ds_read), stage B(T+2){0,1} (Bs[c] retired at P1-end),
    //      MFMA mi4-7 x ni0-1
    if (T <= nt - 3)
      asm volatile("s_waitcnt vmcnt(10)" ::: "memory");
    else if (T == nt - 2)
      asm volatile("s_waitcnt vmcnt(8)" ::: "memory");
    else
      asm volatile("s_waitcnt vmcnt(0)" ::: "memory");
#pragma unroll
    for (int mi = 0; mi < 4; mi++)
#pragma unroll
      for (int ks = 0; ks < 2; ks++) {
        int row = wy * 128 + (mi + 4) * 16 + col;
        a[mi][ks] = *(const short8*)&Ac[row * 64 + (((ks * 4 + quad) ^ (row & 7)) << 3)];
      }
    if (stg) { SB256(c, T + 2, 0); SB256(c, T + 2, 1); }
    __builtin_amdgcn_s_barrier();
    asm volatile("s_waitcnt lgkmcnt(0)" ::: "memory");
    __builtin_amdgcn_s_setprio(1);
#pragma unroll
    for (int mi = 0; mi < 4; mi++)
#pragma unroll
      for (int ni = 0; ni < 2; ni++)
#pragma unroll
        for (int ks = 0; ks < 2; ks++)
          acc[mi + 4][ni] = __builtin_amdgcn_mfma_f32_16x16x32_bf16(a[mi][ks], b[ni][ks],
                                                                    acc[mi + 4][ni], 0, 0, 0);
    __builtin_amdgcn_s_setprio(0);
    __builtin_amdgcn_s_barrier();

    // ---- phase 3: stage B(T+2){2,3} + A(T+2){1,3} (retired at P1/P2-end),
    //      MFMA mi4-7 x ni2-3, group-end wait
    if (stg) {
      SB256(c, T + 2, 2); SB256(c, T + 2, 3);
      SA256(c, T + 2, 1); SA256(c, T + 2, 3);
    }
    __builtin_amdgcn_s_setprio(1);
#pragma unroll
    for (int mi = 0; mi < 4; mi++)
#pragma unroll
      for (int ni = 2; ni < 4; ni++)
#pragma unroll
        for (int ks = 0; ks < 2; ks++)
          acc[mi + 4][ni] = __builtin_amdgcn_mfma_f32_16x16x32_bf16(a[mi][ks], b[ni][ks],
                                                                    acc[mi + 4][ni], 0, 0, 0);
    __builtin_amdgcn_s_setprio(0);
    if (T + 1 < nt) {
      // needs Ae/Ba/Bb(T+1) (issued at T-1): allow Ao(T+1) + this group's stages
      if (T <= nt - 3)
        asm volatile("s_waitcnt vmcnt(10)" ::: "memory");
      else
        asm volatile("s_waitcnt vmcnt(2)" ::: "memory");  // T = nt-2: no stages
      __builtin_amdgcn_s_barrier();
    }
  }
#undef SA256
#undef SB256

#pragma unroll
  for (int mi = 0; mi < 8; mi++)
#pragma unroll
    for (int r = 0; r < 4; r++) {
      long row = m0 + wy * 128 + mi * 16 + quad * 4 + r;
#pragma unroll
      for (int ni = 0; ni < 4; ni++) {
        long cg = n0 + wx * 64 + ni * 16 + col;
        float val = acc[mi][ni][r];
        if (MODE == 1)
          ((unsigned short*)C)[row * N + cg] = f2bf(val);
        else
          ((float*)C)[row * N + cg] = val;
      }
    }
}

// ------- flash attention: S^T trick + register-prefetch double buffer -------
// (unchanged this round -- R3's perfect per-CU sum balance, triples of 34 steps)
__global__ __launch_bounds__(256, 2) void flash(const unsigned short* __restrict__ Q,
                                                const unsigned short* __restrict__ Kg,
                                                const unsigned short* __restrict__ VT,
                                                unsigned short* __restrict__ Og,
                                                float* __restrict__ Opart,
                                                float* __restrict__ lpart) {
  __shared__ unsigned short Ks[64 * 128];  // K tile, xor-swizzled 16B blocks
  __shared__ unsigned short Vs[128 * 64];  // V^T tile (h-major), xor-swizzled
  __shared__ unsigned short Ps[128 * 72];  // P, row l, stride 72
  const int id = blockIdx.x;
  const int g = id & 255, r3 = id >> 8;
  const int kk3 = g & 7, nb = g >> 3;
  const int n = nb & 15, b = nb >> 4;
  int qt, st0, st1, chunk;
  if (r3 == 0) {
    qt = kk3; chunk = -1; st0 = 0; st1 = 2 * qt + 2;
  } else {
    qt = 15 - kk3;
    chunk = r3 - 1;
    const int half = qt + 1;
    st0 = chunk ? half : 0;
    st1 = chunk ? 2 * half : half;
  }
  const int steps_full = 2 * qt + 2;
  const int t = threadIdx.x, lane = t & 63, w = t >> 6;
  const int col = lane & 15, quad = lane >> 4;
  const int kvh = n >> 1;
  const unsigned short* kb = Kg + ((long)b * KH_ + kvh) * L_ * HD_;
  const unsigned short* vtb = VT + ((long)b * KH_ + kvh) * HD_ * L_;  // [h][l]
  const int l0 = qt * 128;
  const unsigned short* qb = Q + (((long)b * NH_ + n) * L_ + l0) * HD_;

  // staging geometry (same lane->address map as the gl_lds path)
  const int rK = t >> 4, blkK = t & 15;  // K: row = i*16+rK, LDS 16B-block = blkK
  const int rV = t >> 3, blkV = t & 7;   // V: row = j*32+rV, LDS 16B-block = blkV

  // wave w owns Q rows [32w, 32w+32)
  short8 qf[2][4];
#pragma unroll
  for (int mi = 0; mi < 2; mi++)
#pragma unroll
    for (int ks = 0; ks < 4; ks++)
      qf[mi][ks] = *(const short8*)(qb + (w * 32 + mi * 16 + col) * 128 + ks * 32 + quad * 8);

  floatx4 o[2][8];
#pragma unroll
  for (int mi = 0; mi < 2; mi++)
#pragma unroll
    for (int nf = 0; nf < 8; nf++) o[mi][nf] = (floatx4)0.0f;
  float lrow[2] = {0.0f, 0.0f};

  // prologue: stage tile st0 via gl_lds, full-drain barrier once
  {
    const long sb = (long)st0 * 64;
#pragma unroll
    for (int i = 0; i < 4; i++) {
      int r = i * 16 + rK;
      int gblk = (blkK & 8) | ((blkK ^ r) & 7);
      gl_lds16(kb + (sb + r) * 128 + gblk * 8, &Ks[(i * 16 + w * 4) * 128]);
    }
#pragma unroll
    for (int j = 0; j < 4; j++) {
      int r = j * 32 + rV;
      int gblk = (blkV ^ r) & 7;
      gl_lds16(vtb + (long)r * L_ + sb + gblk * 8, &Vs[(j * 32 + w * 8) * 64]);
    }
  }
  __syncthreads();

  short8 kpre[4], vpre[4];
  // prefetch tile st0+1
  if (st0 + 1 < st1) {
    const long s0n = (long)(st0 + 1) * 64;
#pragma unroll
    for (int i = 0; i < 4; i++) {
      int r = i * 16 + rK;
      int gblk = (blkK & 8) | ((blkK ^ r) & 7);
      kpre[i] = *(const short8*)(kb + (s0n + r) * 128 + gblk * 8);
    }
#pragma unroll
    for (int j = 0; j < 4; j++) {
      int r = j * 32 + rV;
      int gblk = (blkV ^ r) & 7;
      vpre[j] = *(const short8*)(vtb + (long)r * L_ + s0n + gblk * 8);
    }
  }

  for (int st = st0; st < st1; st++) {
    const int s0 = st * 64;

    // ---- consume tile st ----
    // S^T = K Q^T: A = K-frag (LDS), B = Q-frag (regs). Rows = s, cols = l.
    floatx4 sa[2][4];
#pragma unroll
    for (int mi = 0; mi < 2; mi++)
#pragma unroll
      for (int sf = 0; sf < 4; sf++) sa[mi][sf] = (floatx4)0.0f;
#pragma unroll
    for (int ks = 0; ks < 4; ks++) {
      short8 bf[4];
#pragma unroll
      for (int sf = 0; sf < 4; sf++) {
        int srow = sf * 16 + col;
        int blk = ks * 4 + quad;
        bf[sf] = *(const short8*)&Ks[srow * 128 + (((blk & 8) | ((blk ^ srow) & 7)) << 3)];
      }
#pragma unroll
      for (int mi = 0; mi < 2; mi++)
#pragma unroll
        for (int sf = 0; sf < 4; sf++)
          sa[mi][sf] = __builtin_amdgcn_mfma_f32_16x16x32_bf16(bf[sf], qf[mi][ks],
                                                               sa[mi][sf], 0, 0, 0);
    }

    // causal mask (S^T indices: s = s0+sf*16+quad*4+r, l = l0+w*32+mi*16+col)
    if (st >= steps_full - 2) {
#pragma unroll
      for (int mi = 0; mi < 2; mi++) {
        int lg = l0 + w * 32 + mi * 16 + col;
#pragma unroll
        for (int sf = 0; sf < 4; sf++)
#pragma unroll
          for (int r = 0; r < 4; r++) {
            int sg = s0 + sf * 16 + quad * 4 + r;
            if (sg > lg) sa[mi][sf][r] = -3.0e38f;
          }
      }
    }

    // fixed-max softmax + vectorized P write (one ds_write_b64 per (mi,sf))
#pragma unroll
    for (int mi = 0; mi < 2; mi++)
#pragma unroll
      for (int sf = 0; sf < 4; sf++) {
        short4v pk;
#pragma unroll
        for (int r = 0; r < 4; r++) {
          float pv = exp2f(sa[mi][sf][r] - 17.0f);
          lrow[mi] += pv;
          pk[r] = (short)f2bf(pv);
        }
        *(short4v*)&Ps[(w * 32 + mi * 16 + col) * 72 + sf * 16 + quad * 4] = pk;
      }

    // O += P V at x32 rate (own P rows only -> same-wave LDS ordering)
#pragma unroll
    for (int ks = 0; ks < 2; ks++) {
      short8 pf[2];
#pragma unroll
      for (int mi = 0; mi < 2; mi++)
        pf[mi] = *(const short8*)&Ps[(w * 32 + mi * 16 + col) * 72 + ks * 32 + quad * 8];
      short8 vf[8];
#pragma unroll
      for (int nf = 0; nf < 8; nf++) {
        int h = nf * 16 + col;
        int blk = ks * 4 + quad;
        vf[nf] = *(const short8*)&Vs[h * 64 + ((blk ^ (h & 7)) << 3)];
      }
#pragma unroll
      for (int mi = 0; mi < 2; mi++)
#pragma unroll
        for (int nf = 0; nf < 8; nf++)
          o[mi][nf] = __builtin_amdgcn_mfma_f32_16x16x32_bf16(pf[mi], vf[nf],
                                                              o[mi][nf], 0, 0, 0);
    }

    // ---- rotate buffers: raw barriers keep prefetch loads in flight ----
    barrier_lds_only();  // all waves done reading Ks/Vs (ds ops drained per-wave)
    if (st + 1 < st1) {
      // commit prefetched tile (compiler inserts vmcnt waits for the data deps here)
#pragma unroll
      for (int i = 0; i < 4; i++) {
        int r = i * 16 + rK;
        *(short8*)&Ks[r * 128 + blkK * 8] = kpre[i];
      }
#pragma unroll
      for (int j = 0; j < 4; j++) {
        int r = j * 32 + rV;
        *(short8*)&Vs[r * 64 + blkV * 8] = vpre[j];
      }
      barrier_lds_only();  // new tile visible to all waves
      if (st + 2 < st1) {
        const long s0n = (long)(st + 2) * 64;
#pragma unroll
        for (int i = 0; i < 4; i++) {
          int r = i * 16 + rK;
          int gblk = (blkK & 8) | ((blkK ^ r) & 7);
          kpre[i] = *(const short8*)(kb + (s0n + r) * 128 + gblk * 8);
        }
#pragma unroll
        for (int j = 0; j < 4; j++) {
          int r = j * 32 + rV;
          int gblk = (blkV ^ r) & 7;
          vpre[j] = *(const short8*)(vtb + (long)r * L_ + s0n + gblk * 8);
        }
      }
    }
  }

  if (chunk < 0) {
    // direct path: normalize + bf16 store (lanes 0..15 hold full row sums after
    // the two xors; __shfl(s, quad*4+r) broadcasts row (quad*4+r)'s sum).
#pragma unroll
    for (int mi = 0; mi < 2; mi++) {
      float s = lrow[mi];
      s += __shfl_xor(s, 16);
      s += __shfl_xor(s, 32);
#pragma unroll
      for (int r = 0; r < 4; r++) {
        float inv = 1.0f / __shfl(s, quad * 4 + r);
        int lg = l0 + w * 32 + mi * 16 + quad * 4 + r;
        unsigned short* dst = Og + (((long)b * L_ + lg) * NH_ + n) * HD_;
#pragma unroll
        for (int nf = 0; nf < 8; nf++)
          dst[nf * 16 + col] = f2bf(o[mi][nf][r] * inv);
      }
    }
  } else {
    // partial path: fp32 O (un-normalized) + row sums to workspace
    const int pidx = (((b * NH_ + n) * 8) + (qt - 8)) * 2 + chunk;
    float* Od = Opart + (long)pidx * 16384;  // [128 rows][128 cols] fp32
#pragma unroll
    for (int mi = 0; mi < 2; mi++) {
      float s = lrow[mi];
      s += __shfl_xor(s, 16);
      s += __shfl_xor(s, 32);
      if (lane < 16) lpart[pidx * 128 + w * 32 + mi * 16 + lane] = s;
#pragma unroll
      for (int r = 0; r < 4; r++) {
        int rl = w * 32 + mi * 16 + quad * 4 + r;
#pragma unroll
        for (int nf = 0; nf < 8; nf++)
          Od[rl * 128 + nf * 16 + col] = o[mi][nf][r];
      }
    }
  }
}

// ------- combine: sum 2 s-chunks, normalize, write bf16 ao rows -------
// 256 blocks (b,n,qt8) x 256 threads; thread t: row r=t>>1, cols [(t&1)*64, +64)
__global__ __launch_bounds__(256) void combine(const float* __restrict__ Opart,
                                               const float* __restrict__ lpart,
                                               unsigned short* __restrict__ Og) {
  const int id = blockIdx.x;
  const int q8 = id & 7, n = (id >> 3) & 15, b = id >> 7;
  const int pidx = (((b * NH_ + n) * 8) + q8) * 2;
  const float* OA = Opart + (long)pidx * 16384;
  const float* OB = OA + 16384;
  const int t = threadIdx.x;
  const int r = t >> 1, c0 = (t & 1) * 64;
  const float inv = 1.0f / (lpart[pidx * 128 + r] + lpart[(pidx + 1) * 128 + r]);
  const int lg = (8 + q8) * 128 + r;
  unsigned short* dst = Og + (((long)b * L_ + lg) * NH_ + n) * HD_ + c0;
#pragma unroll
  for (int c = 0; c < 64; c += 4) {
    float4 a = *(const float4*)(OA + r * 128 + c0 + c);
    float4 bb = *(const float4*)(OB + r * 128 + c0 + c);
    ushort4 ov;
    ov.x = f2bf((a.x + bb.x) * inv);
    ov.y = f2bf((a.y + bb.y) * inv);
    ov.z = f2bf((a.z + bb.z) * inv);
    ov.w = f2bf((a.w + bb.w) * inv);
    *(ushort4*)(dst + c) = ov;
  }
}

// ---------------- launcher ----------------
extern "C" void kernel_launch(void* const* d_in, const int* in_sizes, int n_in,
                              void* d_out, int out_size, void* d_ws, size_t ws_size,
                              hipStream_t stream) {
  const float* x = (const float*)d_in[0];
  const int* pos = (const int*)d_in[1];
  // d_in[2] = attn_mask (causal tril) -- implicit in the flash kernel
  const float* wq = (const float*)d_in[3];
  const float* wk = (const float*)d_in[4];
  const float* wv = (const float*)d_in[5];
  const float* wo = (const float*)d_in[6];
  const float* qnw = (const float*)d_in[7];
  const float* knw = (const float*)d_in[8];
  float* out = (float*)d_out;

  // workspace layout (bytes)
  char* ws = (char*)d_ws;
  unsigned short* xb     = (unsigned short*)(ws + 0);          // 16 MiB  (4096 x 2048 bf16)
  unsigned short* wqkv_t = (unsigned short*)(ws + 16777216);   // 16 MiB  (4096 x 2048 bf16)
  unsigned short* wo_t   = (unsigned short*)(ws + 33554432);   //  8 MiB  (2048 x 2048 bf16)
  unsigned short* qkv    = (unsigned short*)(ws + 41943040);   // 32 MiB  (4096 x 4096 bf16)
  unsigned short* q      = (unsigned short*)(ws + 75497472);   // 16 MiB  (B,N,L,H)
  unsigned short* k      = (unsigned short*)(ws + 92274688);   //  8 MiB  (B,K,L,H)
  unsigned short* vT     = (unsigned short*)(ws + 100663296);  //  8 MiB  (B,K,H,L)
  unsigned short* ao     = (unsigned short*)(ws + 109051904);  // 16 MiB  (B,L,N,H)
  if (ws_size < 125829120) return;  // insufficient workspace -> fail loudly

  // flash partials alias regions that are DEAD by flash time:
  //   Opart (32 MiB = 512 tiles x 64 KiB) -> qkv region (consumed by prep2)
  //   lpart (256 KiB)                     -> xb region  (consumed by gemm256)
  float* Opart = (float*)qkv;
  float* lpart = (float*)xb;

  prep1<<<20480, 256, 0, stream>>>(x, wq, wk, wv, wo, xb, wqkv_t, wo_t);
  // QKV GEMM: 256^2 8-phase (grid 16x16 = 256 blocks = exactly 1 block/CU)
  gemm256<1><<<dim3(16, 16), 512, 0, stream>>>(xb, wqkv_t, qkv, 4096, 4096, 2048);
  prep2<<<28672, 256, 0, stream>>>(qkv, pos, qnw, knw, q, k, vT);
  // flash: 1-D grid of 768; triples {g, g+256, g+512} -> one CU, sum = 34 steps.
  flash<<<768, 256, 0, stream>>>(q, k, vT, ao, Opart, lpart);
  combine<<<256, 256, 0, stream>>>(Opart, lpart, ao);
  // Output projection stays 128^2: 256^2 tiling would be only 128 blocks (half
  // the CUs idle) for M=4096, N=2048.
  gemm128<0><<<dim3(16, 32), 256, 0, stream>>>(ao, wo_t, out, 4096, 2048, 2048);
}

// Round 8
// 349.789 us; speedup vs baseline: 1.0105x; 1.0105x over previous
//
#include <hip/hip_runtime.h>
#include <hip/hip_bf16.h>

// Problem constants
#define B_ 2
#define L_ 2048
#define D_ 2048
#define NH_ 16
#define KH_ 8
#define HD_ 128

typedef __attribute__((ext_vector_type(8))) short short8;
typedef __attribute__((ext_vector_type(4))) short short4v;
typedef __attribute__((ext_vector_type(4))) float floatx4;

__device__ __forceinline__ unsigned short f2bf(float f) {
  unsigned u = __float_as_uint(f);
  unsigned r = (u + 0x7fffu + ((u >> 16) & 1u)) >> 16;
  return (unsigned short)r;
}
__device__ __forceinline__ float bf2f(unsigned short h) {
  return __uint_as_float(((unsigned)h) << 16);
}
// Compiler-safe packed bf16 convert (RNE, same bits as f2bf). m240: do NOT
// hand-write v_cvt_pk_bf16_f32 asm (R7 failed correctness doing exactly that);
// the compiler lowers adjacent casts to the packed convert with correct
// hazard handling.
__device__ __forceinline__ unsigned pack_bf16x2(float a, float b) {
  __hip_bfloat162 h = __float22bfloat162_rn(make_float2(a, b));
  return *reinterpret_cast<unsigned*>(&h);
}
__device__ __forceinline__ void gl_lds16(const void* g, void* l) {
  __builtin_amdgcn_global_load_lds(
      (const __attribute__((address_space(1))) unsigned int*)g,
      (__attribute__((address_space(3))) unsigned int*)l, 16, 0, 0);
}
// Raw workgroup barrier that does NOT drain vmcnt: only our own LDS ops must be
// complete. __syncthreads() would emit s_waitcnt vmcnt(0) and kill in-flight
// register prefetch (the m97 barrier-drain stall).
__device__ __forceinline__ void barrier_lds_only() {
  asm volatile("s_waitcnt lgkmcnt(0)" ::: "memory");
  __builtin_amdgcn_s_barrier();
}

// ------- fused prep1: cvt x (fp32->bf16) + transpose+convert all weights -------
__global__ __launch_bounds__(256) void prep1(const float* __restrict__ x,
                                             const float* __restrict__ wq,
                                             const float* __restrict__ wk,
                                             const float* __restrict__ wv,
                                             const float* __restrict__ wo,
                                             unsigned short* __restrict__ xb,
                                             unsigned short* __restrict__ wqkv_t,
                                             unsigned short* __restrict__ wo_t) {
  int id = blockIdx.x;
  int t = threadIdx.x;
  if (id < 8192) {
    long i = ((long)id * 256 + t) * 4;
    float4 v = *(const float4*)(x + i);
    ushort4 o;
    o.x = f2bf(v.x); o.y = f2bf(v.y); o.z = f2bf(v.z); o.w = f2bf(v.w);
    *(ushort4*)(xb + i) = o;
    return;
  }
  id -= 8192;
  __shared__ float tile[32][33];
  const float* in;
  unsigned short* out;
  int C, sh;
  if (id < 4096) {
    in = wq; out = wqkv_t; C = 2048; sh = 6;
  } else if (id < 6144) {
    in = wk; out = wqkv_t + 2048L * 2048; C = 1024; sh = 5; id -= 4096;
  } else if (id < 8192) {
    in = wv; out = wqkv_t + 3072L * 2048; C = 1024; sh = 5; id -= 6144;
  } else {
    in = wo; out = wo_t; C = 2048; sh = 6; id -= 8192;
  }
  int c0 = (id & ((1 << sh) - 1)) * 32, r0 = (id >> sh) * 32;
  int tx = t & 31, ty = t >> 5;  // (32, 8)
#pragma unroll
  for (int i = 0; i < 4; i++)
    tile[ty + i * 8][tx] = in[(long)(r0 + ty + i * 8) * C + c0 + tx];
  __syncthreads();
#pragma unroll
  for (int i = 0; i < 4; i++) {
    int oc = ty + i * 8;
    out[(long)(c0 + oc) * 2048 + r0 + tx] = f2bf(tile[tx][oc]);
  }
}

// ------- fused prep2: rmsrope (q,k) + transpose_v -------
__global__ __launch_bounds__(256) void prep2(const unsigned short* __restrict__ qkv,
                                             const int* __restrict__ pos,
                                             const float* __restrict__ qw,
                                             const float* __restrict__ kw,
                                             unsigned short* __restrict__ qo,
                                             unsigned short* __restrict__ ko,
                                             unsigned short* __restrict__ vT) {
  int id = blockIdx.x;
  int t = threadIdx.x;
  if (id < 24576) {
    const int lane = t & 63, w = t >> 6;
    const int gid = id * 4 + w;  // 0 .. 4096*24-1
    const int row = gid / 24;
    const int hd = gid - row * 24;  // 0..15 q, 16..23 k
    const int b = row >> 11, l = row & 2047;
    const unsigned short* src = qkv + (long)row * 4096 + hd * 128;
    float x0 = bf2f(src[lane]);
    float x1 = bf2f(src[lane + 64]);
    float ss = x0 * x0 + x1 * x1;
#pragma unroll
    for (int off = 32; off; off >>= 1) ss += __shfl_xor(ss, off);
    float inv = 1.0f / sqrtf(ss * (1.0f / 128.0f) + 1e-6f);
    const float* nw = (hd < 16) ? qw : kw;
    x0 = nw[lane] * x0 * inv;
    x1 = nw[lane + 64] * x1 * inv;
    float p = (float)pos[row];
    float ang = p * exp2f((float)lane * -0.31143075889f);  // 1/1e6^(lane/64)
    float s, c;
    sincosf(ang, &s, &c);
    float o0 = x0 * c - x1 * s;
    float o1 = x1 * c + x0 * s;
    unsigned short* dst;
    if (hd < 16) {
      const float QSC = 0.08838834764831845f * 1.4426950408889634f;  // H^-0.5 * log2e
      o0 *= QSC;
      o1 *= QSC;
      dst = qo + (((long)b * NH_ + hd) * L_ + l) * HD_;
    } else {
      dst = ko + (((long)b * KH_ + (hd - 16)) * L_ + l) * HD_;
    }
    dst[lane] = f2bf(o0);
    dst[lane + 64] = f2bf(o1);
    return;
  }
  id -= 24576;
  __shared__ unsigned short tile[32][33];
  int l0 = (id & 63) * 32, h0 = ((id >> 6) & 3) * 32;
  int bk = id >> 8;  // b*8 + kh
  int b = bk >> 3, kh = bk & 7;
  int tx = t & 31, ty = t >> 5;
  const unsigned short* src = qkv + (long)b * L_ * 4096 + 3072 + kh * 128;
#pragma unroll
  for (int i = 0; i < 4; i++)
    tile[ty + i * 8][tx] = src[(long)(l0 + ty + i * 8) * 4096 + h0 + tx];
  __syncthreads();
  unsigned short* dst = vT + (long)bk * HD_ * L_;
#pragma unroll
  for (int i = 0; i < 4; i++)
    dst[(long)(h0 + ty + i * 8) * L_ + l0 + tx] = tile[tx][ty + i * 8];
}

// ---------------- 128x128-tile bf16 MFMA GEMM:  C = A(MxK) * Bt(NxK)^T ----------------
// Kept for the output projection: at 256^2 tiling that GEMM would be only 128
// blocks (half the CUs idle). MODE: 0 = fp32 store, 1 = bf16 store.
template <int MODE>
__global__ __launch_bounds__(256, 3) void gemm128(const unsigned short* __restrict__ A,
                                                  const unsigned short* __restrict__ Bt,
                                                  void* __restrict__ C,
                                                  int M, int N, int K) {
  __shared__ unsigned short As[128 * 64];
  __shared__ unsigned short Bs[128 * 64];
  const int t = threadIdx.x;
  const int lane = t & 63, w = t >> 6;
  const int wy = w >> 1, wx = w & 1;
  const int col = lane & 15, quad = lane >> 4;
  const long m0 = (long)blockIdx.y * 128, n0 = (long)blockIdx.x * 128;
  floatx4 acc[4][4];
#pragma unroll
  for (int i = 0; i < 4; i++)
#pragma unroll
    for (int j = 0; j < 4; j++) acc[i][j] = (floatx4)0.0f;
  const int rs = t >> 3, bs = t & 7;  // staging row / 16B-block
  for (int kt = 0; kt < K; kt += 64) {
#pragma unroll
    for (int i = 0; i < 4; i++) {
      int r = i * 32 + rs;
      gl_lds16(A + (m0 + r) * (long)K + kt + ((bs ^ (r & 7)) << 3),
               &As[(i * 32 + w * 8) * 64]);
      gl_lds16(Bt + (n0 + r) * (long)K + kt + ((bs ^ (r & 7)) << 3),
               &Bs[(i * 32 + w * 8) * 64]);
    }
    __syncthreads();
#pragma unroll
    for (int ks = 0; ks < 2; ks++) {
      short8 af[4], bf[4];
#pragma unroll
      for (int mi = 0; mi < 4; mi++) {
        int row = wy * 64 + mi * 16 + col;
        int blk = ks * 4 + quad;
        af[mi] = *(const short8*)&As[row * 64 + ((blk ^ (row & 7)) << 3)];
      }
#pragma unroll
      for (int ni = 0; ni < 4; ni++) {
        int row = wx * 64 + ni * 16 + col;
        int blk = ks * 4 + quad;
        bf[ni] = *(const short8*)&Bs[row * 64 + ((blk ^ (row & 7)) << 3)];
      }
#pragma unroll
      for (int mi = 0; mi < 4; mi++)
#pragma unroll
        for (int ni = 0; ni < 4; ni++)
          acc[mi][ni] = __builtin_amdgcn_mfma_f32_16x16x32_bf16(af[mi], bf[ni],
                                                                acc[mi][ni], 0, 0, 0);
    }
    __syncthreads();
  }
#pragma unroll
  for (int mi = 0; mi < 4; mi++)
#pragma unroll
    for (int r = 0; r < 4; r++) {
      long row = m0 + wy * 64 + mi * 16 + quad * 4 + r;
#pragma unroll
      for (int ni = 0; ni < 4; ni++) {
        long cg = n0 + wx * 64 + ni * 16 + col;
        float val = acc[mi][ni][r];
        if (MODE == 1)
          ((unsigned short*)C)[row * N + cg] = f2bf(val);
        else
          ((float*)C)[row * N + cg] = val;
      }
    }
}

// ---------------- 256x256-tile 8-phase bf16 MFMA GEMM (T3+T4+T2+T5) ----------------
// R8: reverted to the R1/R3 schedule -- measured 72.4-72.6 us across 8 dispatches
// vs the R6 retiming's 73.7-74.4. R3-vs-R6 A/B already showed wait-retiming is
// not the lever here (both ~37-39% MfmaUtil); keep the consistently faster one.
template <int MODE>
__global__ __launch_bounds__(512, 2) void gemm256(const unsigned short* __restrict__ A,
                                                  const unsigned short* __restrict__ Bt,
                                                  void* __restrict__ C,
                                                  int M, int N, int K) {
  __shared__ unsigned short As[2][256 * 64];
  __shared__ unsigned short Bs[2][256 * 64];
  const int t = threadIdx.x;
  const int lane = t & 63, w = t >> 6;
  const int wy = w >> 2, wx = w & 3;
  const int col = lane & 15, quad = lane >> 4;
  const long m0 = (long)blockIdx.y * 256, n0 = (long)blockIdx.x * 256;
  const int rs = t >> 3, bs = t & 7;  // staging row-in-chunk / 16B-block
  const int nt = K >> 6;              // K tiles of 64 (needs nt >= 2)

#define SA256(bufi, Tt, h)                                                      \
  gl_lds16(A + (m0 + (h) * 64 + rs) * (long)K + (long)(Tt) * 64 +               \
               ((bs ^ (rs & 7)) << 3),                                          \
           &As[bufi][((h) * 64 + w * 8) * 64])
#define SB256(bufi, Tt, h)                                                      \
  gl_lds16(Bt + (n0 + (h) * 64 + rs) * (long)K + (long)(Tt) * 64 +              \
                ((bs ^ (rs & 7)) << 3),                                         \
           &Bs[bufi][((h) * 64 + w * 8) * 64])

  floatx4 acc[8][4];
#pragma unroll
  for (int i = 0; i < 8; i++)
#pragma unroll
    for (int j = 0; j < 4; j++) acc[i][j] = (floatx4)0.0f;

  // prologue: tile0 A+B (8 calls) + tile1 B (4 calls); drain to 4 -> tile0 resident,
  // tile1-B left in flight (matches steady-state group-entry invariant).
  SA256(0, 0, 0); SA256(0, 0, 1); SA256(0, 0, 2); SA256(0, 0, 3);
  SB256(0, 0, 0); SB256(0, 0, 1); SB256(0, 0, 2); SB256(0, 0, 3);
  SB256(1, 1, 0); SB256(1, 1, 1); SB256(1, 1, 2); SB256(1, 1, 3);
  asm volatile("s_waitcnt vmcnt(4)" ::: "memory");
  __builtin_amdgcn_s_barrier();

  for (int T = 0; T < nt; ++T) {
    const int c = T & 1;
    const unsigned short* Ac = As[c];
    const unsigned short* Bc = Bs[c];
    short8 a[4][2], b[4][2];

    // ---- phase 0: read a_lo + b_lo (12 ds_read), stage A(T+1){0,2}, MFMA mi0-3 x ni0-1
#pragma unroll
    for (int mi = 0; mi < 4; mi++)
#pragma unroll
      for (int ks = 0; ks < 2; ks++) {
        int row = wy * 128 + mi * 16 + col;
        a[mi][ks] = *(const short8*)&Ac[row * 64 + (((ks * 4 + quad) ^ (row & 7)) << 3)];
      }
#pragma unroll
    for (int ni = 0; ni < 2; ni++)
#pragma unroll
      for (int ks = 0; ks < 2; ks++) {
        int row = wx * 64 + ni * 16 + col;
        b[ni][ks] = *(const short8*)&Bc[row * 64 + (((ks * 4 + quad) ^ (row & 7)) << 3)];
      }
    if (T + 1 < nt) { SA256(c ^ 1, T + 1, 0); SA256(c ^ 1, T + 1, 2); }
    __builtin_amdgcn_s_barrier();
    asm volatile("s_waitcnt lgkmcnt(0)" ::: "memory");
    __builtin_amdgcn_s_setprio(1);
#pragma unroll
    for (int mi = 0; mi < 4; mi++)
#pragma unroll
      for (int ni = 0; ni < 2; ni++)
#pragma unroll
        for (int ks = 0; ks < 2; ks++)
          acc[mi][ni] = __builtin_amdgcn_mfma_f32_16x16x32_bf16(a[mi][ks], b[ni][ks],
                                                                acc[mi][ni], 0, 0, 0);
    __builtin_amdgcn_s_setprio(0);
    __builtin_amdgcn_s_barrier();

    // ---- phase 1: read b_hi (4 ds_read), stage A(T+1){1,3}, MFMA mi0-3 x ni2-3
#pragma unroll
    for (int ni = 2; ni < 4; ni++)
#pragma unroll
      for (int ks = 0; ks < 2; ks++) {
        int row = wx * 64 + ni * 16 + col;
        b[ni][ks] = *(const short8*)&Bc[row * 64 + (((ks * 4 + quad) ^ (row & 7)) << 3)];
      }
    if (T + 1 < nt) { SA256(c ^ 1, T + 1, 1); SA256(c ^ 1, T + 1, 3); }
    __builtin_amdgcn_s_barrier();
    asm volatile("s_waitcnt lgkmcnt(0)" ::: "memory");
    __builtin_amdgcn_s_setprio(1);
#pragma unroll
    for (int mi = 0; mi < 4; mi++)
#pragma unroll
      for (int ni = 2; ni < 4; ni++)
#pragma unroll
        for (int ks = 0; ks < 2; ks++)
          acc[mi][ni] = __builtin_amdgcn_mfma_f32_16x16x32_bf16(a[mi][ks], b[ni][ks],
                                                                acc[mi][ni], 0, 0, 0);
    __builtin_amdgcn_s_setprio(0);
    __builtin_amdgcn_s_barrier();

    // ---- phase 2: read a_hi (8 ds_read, overwrites a_lo regs), stage B(T+2){0,1},
    //              MFMA mi4-7 x ni0-1. Bs[c] fully retired at P1's end barrier.
#pragma unroll
    for (int mi = 0; mi < 4; mi++)
#pragma unroll
      for (int ks = 0; ks < 2; ks++) {
        int row = wy * 128 + (mi + 4) * 16 + col;
        a[mi][ks] = *(const short8*)&Ac[row * 64 + (((ks * 4 + quad) ^ (row & 7)) << 3)];
      }
    if (T + 2 < nt) { SB256(c, T + 2, 0); SB256(c, T + 2, 1); }
    __builtin_amdgcn_s_barrier();
    asm volatile("s_waitcnt lgkmcnt(0)" ::: "memory");
    __builtin_amdgcn_s_setprio(1);
#pragma unroll
    for (int mi = 0; mi < 4; mi++)
#pragma unroll
      for (int ni = 0; ni < 2; ni++)
#pragma unroll
        for (int ks = 0; ks < 2; ks++)
          acc[mi + 4][ni] = __builtin_amdgcn_mfma_f32_16x16x32_bf16(a[mi][ks], b[ni][ks],
                                                                    acc[mi + 4][ni], 0, 0, 0);
    __builtin_amdgcn_s_setprio(0);
    __builtin_amdgcn_s_barrier();

    // ---- phase 3: no ds_read, stage B(T+2){2,3}, MFMA mi4-7 x ni2-3, group-end wait
    if (T + 2 < nt) { SB256(c, T + 2, 2); SB256(c, T + 2, 3); }
    __builtin_amdgcn_s_setprio(1);
#pragma unroll
    for (int mi = 0; mi < 4; mi++)
#pragma unroll
      for (int ni = 2; ni < 4; ni++)
#pragma unroll
        for (int ks = 0; ks < 2; ks++)
          acc[mi + 4][ni] = __builtin_amdgcn_mfma_f32_16x16x32_bf16(a[mi][ks], b[ni][ks],
                                                                    acc[mi + 4][ni], 0, 0, 0);
    __builtin_amdgcn_s_setprio(0);
    if (T + 1 < nt) {
      // vmcnt(4): everything except B(T+2) landed -> tile T+1 fully resident.
      // Last two groups: no B(T+2) issued, so drain fully once.
      if (T >= nt - 2)
        asm volatile("s_waitcnt vmcnt(0)" ::: "memory");
      else
        asm volatile("s_waitcnt vmcnt(4)" ::: "memory");
      __builtin_amdgcn_s_barrier();
    }
  }
#undef SA256
#undef SB256

#pragma unroll
  for (int mi = 0; mi < 8; mi++)
#pragma unroll
    for (int r = 0; r < 4; r++) {
      long row = m0 + wy * 128 + mi * 16 + quad * 4 + r;
#pragma unroll
      for (int ni = 0; ni < 4; ni++) {
        long cg = n0 + wx * 64 + ni * 16 + col;
        float val = acc[mi][ni][r];
        if (MODE == 1)
          ((unsigned short*)C)[row * N + cg] = f2bf(val);
        else
          ((float*)C)[row * N + cg] = val;
      }
    }
}

// ------- flash attention: S^T trick + register-prefetch double buffer -------
// R8: R1 direct structure (proven 73.9 us; per-CU step-sum = 34 via b-reversed
// qt pairing). VALU cut via COMPILER-generated packed bf16 convert
// (__float22bfloat162_rn) -- R7's hand asm for the same idea failed correctness
// (m240 warned: don't hand-write cvt_pk). lrow accumulator split in two chains.
__global__ __launch_bounds__(256, 2) void flash(const unsigned short* __restrict__ Q,
                                                const unsigned short* __restrict__ Kg,
                                                const unsigned short* __restrict__ VT,
                                                unsigned short* __restrict__ Og) {
  __shared__ unsigned short Ks[64 * 128];  // K tile, xor-swizzled 16B blocks
  __shared__ unsigned short Vs[128 * 64];  // V^T tile (h-major), xor-swizzled
  __shared__ unsigned short Ps[128 * 72];  // P, row l, stride 72
  const int n = blockIdx.y, b = blockIdx.z;
  const int qt = b ? (15 - blockIdx.x) : blockIdx.x;  // per-CU step-sum = 34
  const int t = threadIdx.x, lane = t & 63, w = t >> 6;
  const int col = lane & 15, quad = lane >> 4;
  const int kvh = n >> 1;
  const unsigned short* kb = Kg + ((long)b * KH_ + kvh) * L_ * HD_;
  const unsigned short* vtb = VT + ((long)b * KH_ + kvh) * HD_ * L_;  // [h][l]
  const int l0 = qt * 128;
  const int steps = 2 * qt + 2;
  const unsigned short* qb = Q + (((long)b * NH_ + n) * L_ + l0) * HD_;

  // staging geometry (same lane->address map as the gl_lds path)
  const int rK = t >> 4, blkK = t & 15;  // K: row = i*16+rK, LDS 16B-block = blkK
  const int rV = t >> 3, blkV = t & 7;   // V: row = j*32+rV, LDS 16B-block = blkV

  // wave w owns Q rows [32w, 32w+32)
  short8 qf[2][4];
#pragma unroll
  for (int mi = 0; mi < 2; mi++)
#pragma unroll
    for (int ks = 0; ks < 4; ks++)
      qf[mi][ks] = *(const short8*)(qb + (w * 32 + mi * 16 + col) * 128 + ks * 32 + quad * 8);

  floatx4 o[2][8];
#pragma unroll
  for (int mi = 0; mi < 2; mi++)
#pragma unroll
    for (int nf = 0; nf < 8; nf++) o[mi][nf] = (floatx4)0.0f;
  float lrowA[2] = {0.0f, 0.0f}, lrowB[2] = {0.0f, 0.0f};

  // prologue: stage tile 0 via gl_lds, full-drain barrier once
  {
#pragma unroll
    for (int i = 0; i < 4; i++) {
      int r = i * 16 + rK;
      int gblk = (blkK & 8) | ((blkK ^ r) & 7);
      gl_lds16(kb + (long)r * 128 + gblk * 8, &Ks[(i * 16 + w * 4) * 128]);
    }
#pragma unroll
    for (int j = 0; j < 4; j++) {
      int r = j * 32 + rV;
      int gblk = (blkV ^ r) & 7;
      gl_lds16(vtb + (long)r * L_ + gblk * 8, &Vs[(j * 32 + w * 8) * 64]);
    }
  }
  __syncthreads();

  short8 kpre[4], vpre[4];
  // prefetch tile 1
  if (steps > 1) {
    const int s0n = 64;
#pragma unroll
    for (int i = 0; i < 4; i++) {
      int r = i * 16 + rK;
      int gblk = (blkK & 8) | ((blkK ^ r) & 7);
      kpre[i] = *(const short8*)(kb + (long)(s0n + r) * 128 + gblk * 8);
    }
#pragma unroll
    for (int j = 0; j < 4; j++) {
      int r = j * 32 + rV;
      int gblk = (blkV ^ r) & 7;
      vpre[j] = *(const short8*)(vtb + (long)r * L_ + s0n + gblk * 8);
    }
  }

  for (int st = 0; st < steps; st++) {
    const int s0 = st * 64;

    // ---- consume tile st ----
    // S^T = K Q^T: A = K-frag (LDS), B = Q-frag (regs). Rows = s, cols = l.
    floatx4 sa[2][4];
#pragma unroll
    for (int mi = 0; mi < 2; mi++)
#pragma unroll
      for (int sf = 0; sf < 4; sf++) sa[mi][sf] = (floatx4)0.0f;
#pragma unroll
    for (int ks = 0; ks < 4; ks++) {
      short8 bf[4];
#pragma unroll
      for (int sf = 0; sf < 4; sf++) {
        int srow = sf * 16 + col;
        int blk = ks * 4 + quad;
        bf[sf] = *(const short8*)&Ks[srow * 128 + (((blk & 8) | ((blk ^ srow) & 7)) << 3)];
      }
#pragma unroll
      for (int mi = 0; mi < 2; mi++)
#pragma unroll
        for (int sf = 0; sf < 4; sf++)
          sa[mi][sf] = __builtin_amdgcn_mfma_f32_16x16x32_bf16(bf[sf], qf[mi][ks],
                                                               sa[mi][sf], 0, 0, 0);
    }

    // causal mask (S^T indices: s = s0+sf*16+quad*4+r, l = l0+w*32+mi*16+col)
    if (st >= steps - 2) {
#pragma unroll
      for (int mi = 0; mi < 2; mi++) {
        int lg = l0 + w * 32 + mi * 16 + col;
#pragma unroll
        for (int sf = 0; sf < 4; sf++)
#pragma unroll
          for (int r = 0; r < 4; r++) {
            int sg = s0 + sf * 16 + quad * 4 + r;
            if (sg > lg) sa[mi][sf][r] = -3.0e38f;
          }
      }
    }

    // fixed-max softmax; pack P via compiler packed-convert (one b64 LDS store
    // per (mi,sf)); lrow chains split in two to halve add latency.
#pragma unroll
    for (int mi = 0; mi < 2; mi++)
#pragma unroll
      for (int sf = 0; sf < 4; sf++) {
        float p0 = exp2f(sa[mi][sf][0] - 17.0f);
        float p1 = exp2f(sa[mi][sf][1] - 17.0f);
        float p2 = exp2f(sa[mi][sf][2] - 17.0f);
        float p3 = exp2f(sa[mi][sf][3] - 17.0f);
        lrowA[mi] += p0 + p1;
        lrowB[mi] += p2 + p3;
        uint2 pk;
        pk.x = pack_bf16x2(p0, p1);
        pk.y = pack_bf16x2(p2, p3);
        *(uint2*)&Ps[(w * 32 + mi * 16 + col) * 72 + sf * 16 + quad * 4] = pk;
      }

    // O += P V at x32 rate (own P rows only -> same-wave LDS ordering)
#pragma unroll
    for (int ks = 0; ks < 2; ks++) {
      short8 pf[2];
#pragma unroll
      for (int mi = 0; mi < 2; mi++)
        pf[mi] = *(const short8*)&Ps[(w * 32 + mi * 16 + col) * 72 + ks * 32 + quad * 8];
      short8 vf[8];
#pragma unroll
      for (int nf = 0; nf < 8; nf++) {
        int h = nf * 16 + col;
        int blk = ks * 4 + quad;
        vf[nf] = *(const short8*)&Vs[h * 64 + ((blk ^ (h & 7)) << 3)];
      }
#pragma unroll
      for (int mi = 0; mi < 2; mi++)
#pragma unroll
        for (int nf = 0; nf < 8; nf++)
          o[mi][nf] = __builtin_amdgcn_mfma_f32_16x16x32_bf16(pf[mi], vf[nf],
                                                              o[mi][nf], 0, 0, 0);
    }

    // ---- rotate buffers: raw barriers keep prefetch loads in flight ----
    barrier_lds_only();  // all waves done reading Ks/Vs (ds ops drained per-wave)
    if (st + 1 < steps) {
      // commit prefetched tile (compiler inserts vmcnt waits for the data deps here)
#pragma unroll
      for (int i = 0; i < 4; i++) {
        int r = i * 16 + rK;
        *(short8*)&Ks[r * 128 + blkK * 8] = kpre[i];
      }
#pragma unroll
      for (int j = 0; j < 4; j++) {
        int r = j * 32 + rV;
        *(short8*)&Vs[r * 64 + blkV * 8] = vpre[j];
      }
      barrier_lds_only();  // new tile visible to all waves
      if (st + 2 < steps) {
        const int s0n = (st + 2) * 64;
#pragma unroll
        for (int i = 0; i < 4; i++) {
          int r = i * 16 + rK;
          int gblk = (blkK & 8) | ((blkK ^ r) & 7);
          kpre[i] = *(const short8*)(kb + (long)(s0n + r) * 128 + gblk * 8);
        }
#pragma unroll
        for (int j = 0; j < 4; j++) {
          int r = j * 32 + rV;
          int gblk = (blkV ^ r) & 7;
          vpre[j] = *(const short8*)(vtb + (long)r * L_ + s0n + gblk * 8);
        }
      }
    }
  }

  // epilogue: lrow lives transposed (per col); reduce across quads, then
  // redistribute to C-layout rows (quad*4+r) via one shuffle each.
#pragma unroll
  for (int mi = 0; mi < 2; mi++) {
    float s = lrowA[mi] + lrowB[mi];
    s += __shfl_xor(s, 16);
    s += __shfl_xor(s, 32);  // lanes with col=c now hold full sum for l=..+c
#pragma unroll
    for (int r = 0; r < 4; r++) {
      float inv = 1.0f / __shfl(s, quad * 4 + r);
      int lg = l0 + w * 32 + mi * 16 + quad * 4 + r;
      unsigned short* dst = Og + (((long)b * L_ + lg) * NH_ + n) * HD_;
#pragma unroll
      for (int nf = 0; nf < 8; nf++)
        dst[nf * 16 + col] = f2bf(o[mi][nf][r] * inv);
    }
  }
}

// ---------------- launcher ----------------
extern "C" void kernel_launch(void* const* d_in, const int* in_sizes, int n_in,
                              void* d_out, int out_size, void* d_ws, size_t ws_size,
                              hipStream_t stream) {
  const float* x = (const float*)d_in[0];
  const int* pos = (const int*)d_in[1];
  // d_in[2] = attn_mask (causal tril) -- implicit in the flash kernel
  const float* wq = (const float*)d_in[3];
  const float* wk = (const float*)d_in[4];
  const float* wv = (const float*)d_in[5];
  const float* wo = (const float*)d_in[6];
  const float* qnw = (const float*)d_in[7];
  const float* knw = (const float*)d_in[8];
  float* out = (float*)d_out;

  // workspace layout (bytes)
  char* ws = (char*)d_ws;
  unsigned short* xb     = (unsigned short*)(ws + 0);          // 16 MiB  (4096 x 2048 bf16)
  unsigned short* wqkv_t = (unsigned short*)(ws + 16777216);   // 16 MiB  (4096 x 2048 bf16)
  unsigned short* wo_t   = (unsigned short*)(ws + 33554432);   //  8 MiB  (2048 x 2048 bf16)
  unsigned short* qkv    = (unsigned short*)(ws + 41943040);   // 32 MiB  (4096 x 4096 bf16)
  unsigned short* q      = (unsigned short*)(ws + 75497472);   // 16 MiB  (B,N,L,H)
  unsigned short* k      = (unsigned short*)(ws + 92274688);   //  8 MiB  (B,K,L,H)
  unsigned short* vT     = (unsigned short*)(ws + 100663296);  //  8 MiB  (B,K,H,L)
  unsigned short* ao     = (unsigned short*)(ws + 109051904);  // 16 MiB  (B,L,N,H)
  if (ws_size < 125829120) return;  // insufficient workspace -> fail loudly

  prep1<<<20480, 256, 0, stream>>>(x, wq, wk, wv, wo, xb, wqkv_t, wo_t);
  // QKV GEMM: 256^2 8-phase (grid 16x16 = 256 blocks = exactly 1 block/CU)
  gemm256<1><<<dim3(16, 16), 512, 0, stream>>>(xb, wqkv_t, qkv, 4096, 4096, 2048);
  prep2<<<28672, 256, 0, stream>>>(qkv, pos, qnw, knw, q, k, vT);
  // flash: b-reversed qt pairing -> every CU hosts {qt=x, qt=15-x} = 34 steps.
  flash<<<dim3(16, NH_, B_), 256, 0, stream>>>(q, k, vT, ao);
  // Output projection stays 128^2: 256^2 tiling would be only 128 blocks (half
  // the CUs idle) for M=4096, N=2048.
  gemm128<0><<<dim3(16, 32), 256, 0, stream>>>(ao, wo_t, out, 4096, 2048, 2048);
}

// Round 9
// 334.726 us; speedup vs baseline: 1.0559x; 1.0450x over previous
//
#include <hip/hip_runtime.h>

// Problem constants
#define B_ 2
#define L_ 2048
#define D_ 2048
#define NH_ 16
#define KH_ 8
#define HD_ 128

typedef __attribute__((ext_vector_type(8))) short short8;
typedef __attribute__((ext_vector_type(4))) short short4v;
typedef __attribute__((ext_vector_type(4))) float floatx4;

__device__ __forceinline__ unsigned short f2bf(float f) {
  unsigned u = __float_as_uint(f);
  unsigned r = (u + 0x7fffu + ((u >> 16) & 1u)) >> 16;
  return (unsigned short)r;
}
__device__ __forceinline__ float bf2f(unsigned short h) {
  return __uint_as_float(((unsigned)h) << 16);
}
__device__ __forceinline__ void gl_lds16(const void* g, void* l) {
  __builtin_amdgcn_global_load_lds(
      (const __attribute__((address_space(1))) unsigned int*)g,
      (__attribute__((address_space(3))) unsigned int*)l, 16, 0, 0);
}
// Raw workgroup barrier that does NOT drain vmcnt.
__device__ __forceinline__ void barrier_lds_only() {
  asm volatile("s_waitcnt lgkmcnt(0)" ::: "memory");
  __builtin_amdgcn_s_barrier();
}

// ------- fused prep1: cvt x (fp32->bf16) + transpose+convert all weights -------
__global__ __launch_bounds__(256) void prep1(const float* __restrict__ x,
                                             const float* __restrict__ wq,
                                             const float* __restrict__ wk,
                                             const float* __restrict__ wv,
                                             const float* __restrict__ wo,
                                             unsigned short* __restrict__ xb,
                                             unsigned short* __restrict__ wqkv_t,
                                             unsigned short* __restrict__ wo_t) {
  int id = blockIdx.x;
  int t = threadIdx.x;
  if (id < 8192) {
    long i = ((long)id * 256 + t) * 4;
    float4 v = *(const float4*)(x + i);
    ushort4 o;
    o.x = f2bf(v.x); o.y = f2bf(v.y); o.z = f2bf(v.z); o.w = f2bf(v.w);
    *(ushort4*)(xb + i) = o;
    return;
  }
  id -= 8192;
  __shared__ float tile[32][33];
  const float* in;
  unsigned short* out;
  int C, sh;
  if (id < 4096) {
    in = wq; out = wqkv_t; C = 2048; sh = 6;
  } else if (id < 6144) {
    in = wk; out = wqkv_t + 2048L * 2048; C = 1024; sh = 5; id -= 4096;
  } else if (id < 8192) {
    in = wv; out = wqkv_t + 3072L * 2048; C = 1024; sh = 5; id -= 6144;
  } else {
    in = wo; out = wo_t; C = 2048; sh = 6; id -= 8192;
  }
  int c0 = (id & ((1 << sh) - 1)) * 32, r0 = (id >> sh) * 32;
  int tx = t & 31, ty = t >> 5;  // (32, 8)
#pragma unroll
  for (int i = 0; i < 4; i++)
    tile[ty + i * 8][tx] = in[(long)(r0 + ty + i * 8) * C + c0 + tx];
  __syncthreads();
#pragma unroll
  for (int i = 0; i < 4; i++) {
    int oc = ty + i * 8;
    out[(long)(c0 + oc) * 2048 + r0 + tx] = f2bf(tile[tx][oc]);
  }
}

// ---------------- 128x128-tile bf16 MFMA GEMM:  C = A(MxK) * Bt(NxK)^T ----------------
// Kept for the output projection. MODE: 0 = fp32 store, 1 = bf16 store.
template <int MODE>
__global__ __launch_bounds__(256, 3) void gemm128(const unsigned short* __restrict__ A,
                                                  const unsigned short* __restrict__ Bt,
                                                  void* __restrict__ C,
                                                  int M, int N, int K) {
  __shared__ unsigned short As[128 * 64];
  __shared__ unsigned short Bs[128 * 64];
  const int t = threadIdx.x;
  const int lane = t & 63, w = t >> 6;
  const int wy = w >> 1, wx = w & 1;
  const int col = lane & 15, quad = lane >> 4;
  const long m0 = (long)blockIdx.y * 128, n0 = (long)blockIdx.x * 128;
  floatx4 acc[4][4];
#pragma unroll
  for (int i = 0; i < 4; i++)
#pragma unroll
    for (int j = 0; j < 4; j++) acc[i][j] = (floatx4)0.0f;
  const int rs = t >> 3, bs = t & 7;  // staging row / 16B-block
  for (int kt = 0; kt < K; kt += 64) {
#pragma unroll
    for (int i = 0; i < 4; i++) {
      int r = i * 32 + rs;
      gl_lds16(A + (m0 + r) * (long)K + kt + ((bs ^ (r & 7)) << 3),
               &As[(i * 32 + w * 8) * 64]);
      gl_lds16(Bt + (n0 + r) * (long)K + kt + ((bs ^ (r & 7)) << 3),
               &Bs[(i * 32 + w * 8) * 64]);
    }
    __syncthreads();
#pragma unroll
    for (int ks = 0; ks < 2; ks++) {
      short8 af[4], bf[4];
#pragma unroll
      for (int mi = 0; mi < 4; mi++) {
        int row = wy * 64 + mi * 16 + col;
        int blk = ks * 4 + quad;
        af[mi] = *(const short8*)&As[row * 64 + ((blk ^ (row & 7)) << 3)];
      }
#pragma unroll
      for (int ni = 0; ni < 4; ni++) {
        int row = wx * 64 + ni * 16 + col;
        int blk = ks * 4 + quad;
        bf[ni] = *(const short8*)&Bs[row * 64 + ((blk ^ (row & 7)) << 3)];
      }
#pragma unroll
      for (int mi = 0; mi < 4; mi++)
#pragma unroll
        for (int ni = 0; ni < 4; ni++)
          acc[mi][ni] = __builtin_amdgcn_mfma_f32_16x16x32_bf16(af[mi], bf[ni],
                                                                acc[mi][ni], 0, 0, 0);
    }
    __syncthreads();
  }
#pragma unroll
  for (int mi = 0; mi < 4; mi++)
#pragma unroll
    for (int r = 0; r < 4; r++) {
      long row = m0 + wy * 64 + mi * 16 + quad * 4 + r;
#pragma unroll
      for (int ni = 0; ni < 4; ni++) {
        long cg = n0 + wx * 64 + ni * 16 + col;
        float val = acc[mi][ni][r];
        if (MODE == 1)
          ((unsigned short*)C)[row * N + cg] = f2bf(val);
        else
          ((float*)C)[row * N + cg] = val;
      }
    }
}

// ---------------- 256x256-tile 8-phase bf16 MFMA GEMM (R1/R3 schedule) ----------------
// MODE 2: fused QKV epilogue -- rmsnorm+rope for q/k, LDS transpose for v, written
// directly in flash's layouts. Kills the prep2 kernel + 64MB of qkv round-trip.
// Block (by,bx): rows m0..m0+255 (one batch b), cols 256bx..+255 = exactly 2 heads
// (bx 0-7: q heads 2bx,2bx+1; 8-11: k heads; 12-15: v heads) -> no head spans blocks.
// q/k: Sigma x^2 per row via quad shfl_xor + 4KB LDS cross-wave (wx pair) exchange;
// inv cached in regs; normalized fp32 plane [128][256] staged in the (dead) 128KB
// As/Bs region (2 halves) so rotate-half pairs (d, d+64) -- which live in different
// waves -- can be read per-lane; one sincos per lane serves both heads; stores are
// 128B-contiguous rows. Full fp32 path (MORE accurate than the old bf16 round-trip).
// v: bf16 transpose via the same LDS with ^((c&15)<<4) swizzle (r-packed b64 writes,
// rl-contiguous ushort4 reads) -> perfectly coalesced 512B vT stores.
template <int MODE>
__global__ __launch_bounds__(512, 2) void gemm256(const unsigned short* __restrict__ A,
                                                  const unsigned short* __restrict__ Bt,
                                                  void* __restrict__ C,
                                                  int M, int N, int K,
                                                  unsigned short* __restrict__ qptr,
                                                  unsigned short* __restrict__ kptr,
                                                  unsigned short* __restrict__ vTptr,
                                                  const int* __restrict__ posp,
                                                  const float* __restrict__ qwp,
                                                  const float* __restrict__ kwp) {
  __shared__ unsigned short SMu[4][256 * 64];  // [0..1]=As dbuf, [2..3]=Bs dbuf; 128KB
  const int t = threadIdx.x;
  const int lane = t & 63, w = t >> 6;
  const int wy = w >> 2, wx = w & 3;
  const int col = lane & 15, quad = lane >> 4;
  const long m0 = (long)blockIdx.y * 256, n0 = (long)blockIdx.x * 256;
  const int rs = t >> 3, bs = t & 7;  // staging row-in-chunk / 16B-block
  const int nt = K >> 6;              // K tiles of 64 (needs nt >= 2)

#define SA256(bufi, Tt, h)                                                      \
  gl_lds16(A + (m0 + (h) * 64 + rs) * (long)K + (long)(Tt) * 64 +               \
               ((bs ^ (rs & 7)) << 3),                                          \
           &SMu[bufi][((h) * 64 + w * 8) * 64])
#define SB256(bufi, Tt, h)                                                      \
  gl_lds16(Bt + (n0 + (h) * 64 + rs) * (long)K + (long)(Tt) * 64 +              \
                ((bs ^ (rs & 7)) << 3),                                         \
           &SMu[2 + (bufi)][((h) * 64 + w * 8) * 64])

  floatx4 acc[8][4];
#pragma unroll
  for (int i = 0; i < 8; i++)
#pragma unroll
    for (int j = 0; j < 4; j++) acc[i][j] = (floatx4)0.0f;

  // prologue: tile0 A+B (8 calls) + tile1 B (4 calls); drain to 4.
  SA256(0, 0, 0); SA256(0, 0, 1); SA256(0, 0, 2); SA256(0, 0, 3);
  SB256(0, 0, 0); SB256(0, 0, 1); SB256(0, 0, 2); SB256(0, 0, 3);
  SB256(1, 1, 0); SB256(1, 1, 1); SB256(1, 1, 2); SB256(1, 1, 3);
  asm volatile("s_waitcnt vmcnt(4)" ::: "memory");
  __builtin_amdgcn_s_barrier();

  for (int T = 0; T < nt; ++T) {
    const int c = T & 1;
    const unsigned short* Ac = SMu[c];
    const unsigned short* Bc = SMu[2 + c];
    short8 a[4][2], b[4][2];

    // ---- phase 0: read a_lo + b_lo, stage A(T+1){0,2}, MFMA mi0-3 x ni0-1
#pragma unroll
    for (int mi = 0; mi < 4; mi++)
#pragma unroll
      for (int ks = 0; ks < 2; ks++) {
        int row = wy * 128 + mi * 16 + col;
        a[mi][ks] = *(const short8*)&Ac[row * 64 + (((ks * 4 + quad) ^ (row & 7)) << 3)];
      }
#pragma unroll
    for (int ni = 0; ni < 2; ni++)
#pragma unroll
      for (int ks = 0; ks < 2; ks++) {
        int row = wx * 64 + ni * 16 + col;
        b[ni][ks] = *(const short8*)&Bc[row * 64 + (((ks * 4 + quad) ^ (row & 7)) << 3)];
      }
    if (T + 1 < nt) { SA256(c ^ 1, T + 1, 0); SA256(c ^ 1, T + 1, 2); }
    __builtin_amdgcn_s_barrier();
    asm volatile("s_waitcnt lgkmcnt(0)" ::: "memory");
    __builtin_amdgcn_s_setprio(1);
#pragma unroll
    for (int mi = 0; mi < 4; mi++)
#pragma unroll
      for (int ni = 0; ni < 2; ni++)
#pragma unroll
        for (int ks = 0; ks < 2; ks++)
          acc[mi][ni] = __builtin_amdgcn_mfma_f32_16x16x32_bf16(a[mi][ks], b[ni][ks],
                                                                acc[mi][ni], 0, 0, 0);
    __builtin_amdgcn_s_setprio(0);
    __builtin_amdgcn_s_barrier();

    // ---- phase 1: read b_hi, stage A(T+1){1,3}, MFMA mi0-3 x ni2-3
#pragma unroll
    for (int ni = 2; ni < 4; ni++)
#pragma unroll
      for (int ks = 0; ks < 2; ks++) {
        int row = wx * 64 + ni * 16 + col;
        b[ni][ks] = *(const short8*)&Bc[row * 64 + (((ks * 4 + quad) ^ (row & 7)) << 3)];
      }
    if (T + 1 < nt) { SA256(c ^ 1, T + 1, 1); SA256(c ^ 1, T + 1, 3); }
    __builtin_amdgcn_s_barrier();
    asm volatile("s_waitcnt lgkmcnt(0)" ::: "memory");
    __builtin_amdgcn_s_setprio(1);
#pragma unroll
    for (int mi = 0; mi < 4; mi++)
#pragma unroll
      for (int ni = 2; ni < 4; ni++)
#pragma unroll
        for (int ks = 0; ks < 2; ks++)
          acc[mi][ni] = __builtin_amdgcn_mfma_f32_16x16x32_bf16(a[mi][ks], b[ni][ks],
                                                                acc[mi][ni], 0, 0, 0);
    __builtin_amdgcn_s_setprio(0);
    __builtin_amdgcn_s_barrier();

    // ---- phase 2: read a_hi, stage B(T+2){0,1}, MFMA mi4-7 x ni0-1
#pragma unroll
    for (int mi = 0; mi < 4; mi++)
#pragma unroll
      for (int ks = 0; ks < 2; ks++) {
        int row = wy * 128 + (mi + 4) * 16 + col;
        a[mi][ks] = *(const short8*)&Ac[row * 64 + (((ks * 4 + quad) ^ (row & 7)) << 3)];
      }
    if (T + 2 < nt) { SB256(c, T + 2, 0); SB256(c, T + 2, 1); }
    __builtin_amdgcn_s_barrier();
    asm volatile("s_waitcnt lgkmcnt(0)" ::: "memory");
    __builtin_amdgcn_s_setprio(1);
#pragma unroll
    for (int mi = 0; mi < 4; mi++)
#pragma unroll
      for (int ni = 0; ni < 2; ni++)
#pragma unroll
        for (int ks = 0; ks < 2; ks++)
          acc[mi + 4][ni] = __builtin_amdgcn_mfma_f32_16x16x32_bf16(a[mi][ks], b[ni][ks],
                                                                    acc[mi + 4][ni], 0, 0, 0);
    __builtin_amdgcn_s_setprio(0);
    __builtin_amdgcn_s_barrier();

    // ---- phase 3: stage B(T+2){2,3}, MFMA mi4-7 x ni2-3, group-end wait
    if (T + 2 < nt) { SB256(c, T + 2, 2); SB256(c, T + 2, 3); }
    __builtin_amdgcn_s_setprio(1);
#pragma unroll
    for (int mi = 0; mi < 4; mi++)
#pragma unroll
      for (int ni = 2; ni < 4; ni++)
#pragma unroll
        for (int ks = 0; ks < 2; ks++)
          acc[mi + 4][ni] = __builtin_amdgcn_mfma_f32_16x16x32_bf16(a[mi][ks], b[ni][ks],
                                                                    acc[mi + 4][ni], 0, 0, 0);
    __builtin_amdgcn_s_setprio(0);
    if (T + 1 < nt) {
      if (T >= nt - 2)
        asm volatile("s_waitcnt vmcnt(0)" ::: "memory");
      else
        asm volatile("s_waitcnt vmcnt(4)" ::: "memory");
      __builtin_amdgcn_s_barrier();
    }
  }
#undef SA256
#undef SB256

  if (MODE == 2) {
    // ================= fused QKV epilogue =================
    const int bx = blockIdx.x;
    const int bb = (int)(m0 >> 11);   // batch
    const int l0r = (int)(m0 & 2047); // base sequence position
    __syncthreads();  // all waves done with As/Bs; LDS reusable

    if (bx >= 12) {
      // ---- V: bf16 transpose via LDS, coalesced vT stores ----
      const int khb = (bx - 12) * 2;
      unsigned short* Vt = (unsigned short*)SMu;  // [256 c][256 rl], xor-swizzled
#pragma unroll
      for (int mi = 0; mi < 8; mi++)
#pragma unroll
        for (int ni = 0; ni < 4; ni++) {
          int cc = wx * 64 + ni * 16 + col;
          int rbase = wy * 128 + mi * 16 + quad * 4;
          short4v pk;
#pragma unroll
          for (int r = 0; r < 4; r++) pk[r] = (short)f2bf(acc[mi][ni][r]);
          *(short4v*)&Vt[cc * 256 + (rbase ^ ((cc & 15) << 4))] = pk;
        }
      __syncthreads();
      // wave w stores h-rows w*32 .. w*32+31 (512B contiguous each)
      for (int i = 0; i < 32; i++) {
        int cc = w * 32 + i;
        int hloc = cc & 127;
        int khh = khb + (cc >> 7);
        ushort4 v4 = *(const ushort4*)&Vt[cc * 256 + ((lane * 4) ^ ((cc & 15) << 4))];
        *(ushort4*)&vTptr[(((long)bb * KH_ + khh) * HD_ + hloc) * (long)L_ + l0r + lane * 4] = v4;
      }
      return;
    }

    // ---- Q/K: rms + rope fused ----
    const bool isq = (bx < 8);
    const float* nwp = isq ? qwp : kwp;
    float* PART = (float*)SMu;  // [256 rows][4 wx] fp32 = 4KB
    // 1) per-row Sigma x^2: quad-local shfl reduce, lane col==0 writes partial
#pragma unroll
    for (int mi = 0; mi < 8; mi++)
#pragma unroll
      for (int r = 0; r < 4; r++) {
        float s = acc[mi][0][r] * acc[mi][0][r] + acc[mi][1][r] * acc[mi][1][r] +
                  acc[mi][2][r] * acc[mi][2][r] + acc[mi][3][r] * acc[mi][3][r];
        s += __shfl_xor(s, 1);
        s += __shfl_xor(s, 2);
        s += __shfl_xor(s, 4);
        s += __shfl_xor(s, 8);
        if (col == 0)
          PART[((wy * 128 + mi * 16 + quad * 4 + r) << 2) + wx] = s;
      }
    __syncthreads();
    // 2) inv per owned row, cached in regs (head = wx pair {0,1} or {2,3})
    float inv[8][4];
    {
      const int wp = (wx >> 1) << 1;
#pragma unroll
      for (int mi = 0; mi < 8; mi++)
#pragma unroll
        for (int r = 0; r < 4; r++) {
          int lr = wy * 128 + mi * 16 + quad * 4 + r;
          float ss = PART[(lr << 2) + wp] + PART[(lr << 2) + wp + 1];
          inv[mi][r] = 1.0f / sqrtf(ss * (1.0f / 128.0f) + 1e-6f);
        }
    }
    __syncthreads();  // PART dead; SM becomes the fp32 plane
    float* plane = (float*)SMu;  // [128 rows][256 cols] = 128KB
    const float nw0 = nwp[lane], nw1 = nwp[lane + 64];
    const float QSC = 0.08838834764831845f * 1.4426950408889634f;  // H^-0.5 * log2e
    for (int hh = 0; hh < 2; hh++) {
      if (wy == hh) {
#pragma unroll
        for (int mi = 0; mi < 8; mi++)
#pragma unroll
          for (int ni = 0; ni < 4; ni++) {
            int cc = wx * 64 + ni * 16 + col;
#pragma unroll
            for (int r = 0; r < 4; r++)
              plane[(mi * 16 + quad * 4 + r) * 256 + cc] = acc[mi][ni][r] * inv[mi][r];
          }
      }
      __syncthreads();
      // rope + store: wave w handles local rows w*16 .. w*16+15
      for (int i = 0; i < 16; i++) {
        int lr = w * 16 + i;
        int lg = l0r + hh * 128 + lr;
        float x0a = plane[lr * 256 + lane];
        float x1a = plane[lr * 256 + lane + 64];
        float x0b = plane[lr * 256 + 128 + lane];
        float x1b = plane[lr * 256 + 192 + lane];
        float p = (float)posp[bb * L_ + lg];
        float ang = p * exp2f((float)lane * -0.31143075889f);  // 1/1e6^(lane/64)
        float sv, cv;
        sincosf(ang, &sv, &cv);
        x0a *= nw0; x1a *= nw1; x0b *= nw0; x1b *= nw1;
        float o0a = x0a * cv - x1a * sv, o1a = x1a * cv + x0a * sv;
        float o0b = x0b * cv - x1b * sv, o1b = x1b * cv + x0b * sv;
        unsigned short* d0;
        if (isq) {
          o0a *= QSC; o1a *= QSC; o0b *= QSC; o1b *= QSC;
          d0 = qptr + (((long)bb * NH_ + bx * 2) * L_ + lg) * HD_;
        } else {
          d0 = kptr + (((long)bb * KH_ + (bx - 8) * 2) * L_ + lg) * HD_;
        }
        d0[lane] = f2bf(o0a);
        d0[lane + 64] = f2bf(o1a);
        d0[(long)L_ * HD_ + lane] = f2bf(o0b);
        d0[(long)L_ * HD_ + lane + 64] = f2bf(o1b);
      }
      __syncthreads();  // plane free before the other half overwrites it
    }
    return;
  }

  // normal C write (MODE 0/1)
#pragma unroll
  for (int mi = 0; mi < 8; mi++)
#pragma unroll
    for (int r = 0; r < 4; r++) {
      long row = m0 + wy * 128 + mi * 16 + quad * 4 + r;
#pragma unroll
      for (int ni = 0; ni < 4; ni++) {
        long cg = n0 + wx * 64 + ni * 16 + col;
        float val = acc[mi][ni][r];
        if (MODE == 1)
          ((unsigned short*)C)[row * N + cg] = f2bf(val);
        else
          ((float*)C)[row * N + cg] = val;
      }
    }
}

// ------- flash attention: S^T trick + register-prefetch double buffer -------
// (unchanged -- R1 direct structure, per-CU step-sum = 34 via b-reversed qt)
__global__ __launch_bounds__(256, 2) void flash(const unsigned short* __restrict__ Q,
                                                const unsigned short* __restrict__ Kg,
                                                const unsigned short* __restrict__ VT,
                                                unsigned short* __restrict__ Og) {
  __shared__ unsigned short Ks[64 * 128];  // K tile, xor-swizzled 16B blocks
  __shared__ unsigned short Vs[128 * 64];  // V^T tile (h-major), xor-swizzled
  __shared__ unsigned short Ps[128 * 72];  // P, row l, stride 72
  const int n = blockIdx.y, b = blockIdx.z;
  const int qt = b ? (15 - blockIdx.x) : blockIdx.x;  // per-CU step-sum = 34
  const int t = threadIdx.x, lane = t & 63, w = t >> 6;
  const int col = lane & 15, quad = lane >> 4;
  const int kvh = n >> 1;
  const unsigned short* kb = Kg + ((long)b * KH_ + kvh) * L_ * HD_;
  const unsigned short* vtb = VT + ((long)b * KH_ + kvh) * HD_ * L_;  // [h][l]
  const int l0 = qt * 128;
  const int steps = 2 * qt + 2;
  const unsigned short* qb = Q + (((long)b * NH_ + n) * L_ + l0) * HD_;

  const int rK = t >> 4, blkK = t & 15;
  const int rV = t >> 3, blkV = t & 7;

  short8 qf[2][4];
#pragma unroll
  for (int mi = 0; mi < 2; mi++)
#pragma unroll
    for (int ks = 0; ks < 4; ks++)
      qf[mi][ks] = *(const short8*)(qb + (w * 32 + mi * 16 + col) * 128 + ks * 32 + quad * 8);

  floatx4 o[2][8];
#pragma unroll
  for (int mi = 0; mi < 2; mi++)
#pragma unroll
    for (int nf = 0; nf < 8; nf++) o[mi][nf] = (floatx4)0.0f;
  float lrowA[2] = {0.0f, 0.0f}, lrowB[2] = {0.0f, 0.0f};

  {
#pragma unroll
    for (int i = 0; i < 4; i++) {
      int r = i * 16 + rK;
      int gblk = (blkK & 8) | ((blkK ^ r) & 7);
      gl_lds16(kb + (long)r * 128 + gblk * 8, &Ks[(i * 16 + w * 4) * 128]);
    }
#pragma unroll
    for (int j = 0; j < 4; j++) {
      int r = j * 32 + rV;
      int gblk = (blkV ^ r) & 7;
      gl_lds16(vtb + (long)r * L_ + gblk * 8, &Vs[(j * 32 + w * 8) * 64]);
    }
  }
  __syncthreads();

  short8 kpre[4], vpre[4];
  if (steps > 1) {
    const int s0n = 64;
#pragma unroll
    for (int i = 0; i < 4; i++) {
      int r = i * 16 + rK;
      int gblk = (blkK & 8) | ((blkK ^ r) & 7);
      kpre[i] = *(const short8*)(kb + (long)(s0n + r) * 128 + gblk * 8);
    }
#pragma unroll
    for (int j = 0; j < 4; j++) {
      int r = j * 32 + rV;
      int gblk = (blkV ^ r) & 7;
      vpre[j] = *(const short8*)(vtb + (long)r * L_ + s0n + gblk * 8);
    }
  }

  for (int st = 0; st < steps; st++) {
    const int s0 = st * 64;
    floatx4 sa[2][4];
#pragma unroll
    for (int mi = 0; mi < 2; mi++)
#pragma unroll
      for (int sf = 0; sf < 4; sf++) sa[mi][sf] = (floatx4)0.0f;
#pragma unroll
    for (int ks = 0; ks < 4; ks++) {
      short8 bf[4];
#pragma unroll
      for (int sf = 0; sf < 4; sf++) {
        int srow = sf * 16 + col;
        int blk = ks * 4 + quad;
        bf[sf] = *(const short8*)&Ks[srow * 128 + (((blk & 8) | ((blk ^ srow) & 7)) << 3)];
      }
#pragma unroll
      for (int mi = 0; mi < 2; mi++)
#pragma unroll
        for (int sf = 0; sf < 4; sf++)
          sa[mi][sf] = __builtin_amdgcn_mfma_f32_16x16x32_bf16(bf[sf], qf[mi][ks],
                                                               sa[mi][sf], 0, 0, 0);
    }

    if (st >= steps - 2) {
#pragma unroll
      for (int mi = 0; mi < 2; mi++) {
        int lg = l0 + w * 32 + mi * 16 + col;
#pragma unroll
        for (int sf = 0; sf < 4; sf++)
#pragma unroll
          for (int r = 0; r < 4; r++) {
            int sg = s0 + sf * 16 + quad * 4 + r;
            if (sg > lg) sa[mi][sf][r] = -3.0e38f;
          }
      }
    }

#pragma unroll
    for (int mi = 0; mi < 2; mi++)
#pragma unroll
      for (int sf = 0; sf < 4; sf++) {
        float p0 = exp2f(sa[mi][sf][0] - 17.0f);
        float p1 = exp2f(sa[mi][sf][1] - 17.0f);
        float p2 = exp2f(sa[mi][sf][2] - 17.0f);
        float p3 = exp2f(sa[mi][sf][3] - 17.0f);
        lrowA[mi] += p0 + p1;
        lrowB[mi] += p2 + p3;
        short4v pk;
        pk[0] = (short)f2bf(p0);
        pk[1] = (short)f2bf(p1);
        pk[2] = (short)f2bf(p2);
        pk[3] = (short)f2bf(p3);
        *(short4v*)&Ps[(w * 32 + mi * 16 + col) * 72 + sf * 16 + quad * 4] = pk;
      }

#pragma unroll
    for (int ks = 0; ks < 2; ks++) {
      short8 pf[2];
#pragma unroll
      for (int mi = 0; mi < 2; mi++)
        pf[mi] = *(const short8*)&Ps[(w * 32 + mi * 16 + col) * 72 + ks * 32 + quad * 8];
      short8 vf[8];
#pragma unroll
      for (int nf = 0; nf < 8; nf++) {
        int h = nf * 16 + col;
        int blk = ks * 4 + quad;
        vf[nf] = *(const short8*)&Vs[h * 64 + ((blk ^ (h & 7)) << 3)];
      }
#pragma unroll
      for (int mi = 0; mi < 2; mi++)
#pragma unroll
        for (int nf = 0; nf < 8; nf++)
          o[mi][nf] = __builtin_amdgcn_mfma_f32_16x16x32_bf16(pf[mi], vf[nf],
                                                              o[mi][nf], 0, 0, 0);
    }

    barrier_lds_only();
    if (st + 1 < steps) {
#pragma unroll
      for (int i = 0; i < 4; i++) {
        int r = i * 16 + rK;
        *(short8*)&Ks[r * 128 + blkK * 8] = kpre[i];
      }
#pragma unroll
      for (int j = 0; j < 4; j++) {
        int r = j * 32 + rV;
        *(short8*)&Vs[r * 64 + blkV * 8] = vpre[j];
      }
      barrier_lds_only();
      if (st + 2 < steps) {
        const int s0n = (st + 2) * 64;
#pragma unroll
        for (int i = 0; i < 4; i++) {
          int r = i * 16 + rK;
          int gblk = (blkK & 8) | ((blkK ^ r) & 7);
          kpre[i] = *(const short8*)(kb + (long)(s0n + r) * 128 + gblk * 8);
        }
#pragma unroll
        for (int j = 0; j < 4; j++) {
          int r = j * 32 + rV;
          int gblk = (blkV ^ r) & 7;
          vpre[j] = *(const short8*)(vtb + (long)r * L_ + s0n + gblk * 8);
        }
      }
    }
  }

#pragma unroll
  for (int mi = 0; mi < 2; mi++) {
    float s = lrowA[mi] + lrowB[mi];
    s += __shfl_xor(s, 16);
    s += __shfl_xor(s, 32);
#pragma unroll
    for (int r = 0; r < 4; r++) {
      float inv = 1.0f / __shfl(s, quad * 4 + r);
      int lg = l0 + w * 32 + mi * 16 + quad * 4 + r;
      unsigned short* dst = Og + (((long)b * L_ + lg) * NH_ + n) * HD_;
#pragma unroll
      for (int nf = 0; nf < 8; nf++)
        dst[nf * 16 + col] = f2bf(o[mi][nf][r] * inv);
    }
  }
}

// ---------------- launcher ----------------
extern "C" void kernel_launch(void* const* d_in, const int* in_sizes, int n_in,
                              void* d_out, int out_size, void* d_ws, size_t ws_size,
                              hipStream_t stream) {
  const float* x = (const float*)d_in[0];
  const int* pos = (const int*)d_in[1];
  // d_in[2] = attn_mask (causal tril) -- implicit in the flash kernel
  const float* wq = (const float*)d_in[3];
  const float* wk = (const float*)d_in[4];
  const float* wv = (const float*)d_in[5];
  const float* wo = (const float*)d_in[6];
  const float* qnw = (const float*)d_in[7];
  const float* knw = (const float*)d_in[8];
  float* out = (float*)d_out;

  // workspace layout (bytes)
  char* ws = (char*)d_ws;
  unsigned short* xb     = (unsigned short*)(ws + 0);          // 16 MiB  (4096 x 2048 bf16)
  unsigned short* wqkv_t = (unsigned short*)(ws + 16777216);   // 16 MiB  (4096 x 2048 bf16)
  unsigned short* wo_t   = (unsigned short*)(ws + 33554432);   //  8 MiB  (2048 x 2048 bf16)
  // (qkv region at +41943040 is now unused -- prep2 fused into gemm256 epilogue)
  unsigned short* q      = (unsigned short*)(ws + 75497472);   // 16 MiB  (B,N,L,H)
  unsigned short* k      = (unsigned short*)(ws + 92274688);   //  8 MiB  (B,K,L,H)
  unsigned short* vT     = (unsigned short*)(ws + 100663296);  //  8 MiB  (B,K,H,L)
  unsigned short* ao     = (unsigned short*)(ws + 109051904);  // 16 MiB  (B,L,N,H)
  if (ws_size < 125829120) return;  // insufficient workspace -> fail loudly

  prep1<<<20480, 256, 0, stream>>>(x, wq, wk, wv, wo, xb, wqkv_t, wo_t);
  // QKV GEMM with fused rmsrope/transpose epilogue (kills prep2 + 64MB round-trip)
  gemm256<2><<<dim3(16, 16), 512, 0, stream>>>(xb, wqkv_t, nullptr, 4096, 4096, 2048,
                                               q, k, vT, pos, qnw, knw);
  // flash: b-reversed qt pairing -> every CU hosts {qt=x, qt=15-x} = 34 steps.
  flash<<<dim3(16, NH_, B_), 256, 0, stream>>>(q, k, vT, ao);
  // Output projection stays 128^2 (512 blocks keep all CUs busy).
  gemm128<0><<<dim3(16, 32), 256, 0, stream>>>(ao, wo_t, out, 4096, 2048, 2048);
}